// Round 2
// baseline (260.875 us; speedup 1.0000x reference)
//
#include <hip/hip_runtime.h>

#define DD 128

typedef float f32x4 __attribute__((ext_vector_type(4)));

// 8 lanes per row, 16 consecutive elements per lane.
// Each 16-aligned one-hot slice (ALU_LO/ALU_HI/AX_CARRY) lives entirely in one
// lane -> argmax is local VALU, no cross-lane butterfly. Only 4 broadcasts per
// row group. Targets t0 in [64,80) = lane 4's slice, t1 in [80,96) = lane 5's.
__global__ __launch_bounds__(256) void byteshift_kernel(const float* __restrict__ x,
                                                        float* __restrict__ out,
                                                        int n_rows) {
    int tid = blockIdx.x * blockDim.x + threadIdx.x;
    int lane = tid & 7;                  // lane within the 8-lane row group
    int row = tid >> 3;
    if (row >= n_rows) return;

    const f32x4* xr = (const f32x4*)(x + (size_t)row * DD) + lane * 4;
    f32x4 v0 = __builtin_nontemporal_load(xr + 0);
    f32x4 v1 = __builtin_nontemporal_load(xr + 1);
    f32x4 v2 = __builtin_nontemporal_load(xr + 2);
    f32x4 v3 = __builtin_nontemporal_load(xr + 3);

    float f[16] = {v0.x, v0.y, v0.z, v0.w, v1.x, v1.y, v1.z, v1.w,
                   v2.x, v2.y, v2.z, v2.w, v3.x, v3.y, v3.z, v3.w};

    // local argmax over this lane's 16 elements (= one full slice).
    // '>' keeps the first occurrence, matching jnp.argmax tie-break.
    float m = f[0]; int mi = 0;
    #pragma unroll
    for (int j = 1; j < 16; ++j)
        if (f[j] > m) { m = f[j]; mi = j; }

    // flags live in lane 0: d0 MARK >=0.5, d1 SHL >0.5, d2 SHR >0.5
    int flags = (f[0] >= 0.5f ? 1 : 0) | (f[1] > 0.5f ? 2 : 0) | (f[2] > 0.5f ? 4 : 0);
    flags     = __shfl(flags, 0, 8);
    int n_lo  = __shfl(mi, 1, 8);        // ALU_LO nibble   (d in [16,32), d&15)
    int n_hi  = __shfl(mi, 2, 8);        // ALU_HI nibble   (d in [32,48))
    int n_sh  = __shfl(mi, 3, 8);        // shift           (d in [48,64), <=15 so min(.,31) is a no-op)

    int value   = n_lo | (n_hi << 4);    // 0..255
    bool shl    = (flags & 2) != 0;
    bool active = (flags & 1) && (flags & 6);
    int result  = shl ? ((value << n_sh) & 255) : (value >> n_sh);

    int t0 = 64 + (result & 15);         // always in lane 4's slice
    int t1 = 80 + (result >> 4);         // always in lane 5's slice
    int dbase = lane << 4;
    int tsel  = (dbase == 80) ? t1 : t0; // lane 5 checks t1, everyone else t0
    int r     = active ? (tsel - dbase) : -1;   // 0..15 only on the matching lane

    #pragma unroll
    for (int j = 0; j < 16; ++j)
        if (r == j) f[j] += 2.0f;

    f32x4* orow = (f32x4*)(out + (size_t)row * DD) + lane * 4;
    f32x4 o0 = {f[0],  f[1],  f[2],  f[3]};
    f32x4 o1 = {f[4],  f[5],  f[6],  f[7]};
    f32x4 o2 = {f[8],  f[9],  f[10], f[11]};
    f32x4 o3 = {f[12], f[13], f[14], f[15]};
    __builtin_nontemporal_store(o0, orow + 0);
    __builtin_nontemporal_store(o1, orow + 1);
    __builtin_nontemporal_store(o2, orow + 2);
    __builtin_nontemporal_store(o3, orow + 3);
}

extern "C" void kernel_launch(void* const* d_in, const int* in_sizes, int n_in,
                              void* d_out, int out_size, void* d_ws, size_t ws_size,
                              hipStream_t stream) {
    const float* x = (const float*)d_in[0];
    float* out = (float*)d_out;
    int n_rows = in_sizes[0] / DD;       // B*S = 262144
    int threads = 256;                   // 32 rows per block
    int total = n_rows * 8;
    int blocks = (total + threads - 1) / threads;
    hipLaunchKernelGGL(byteshift_kernel, dim3(blocks), dim3(threads), 0, stream,
                       x, out, n_rows);
}

// Round 3
// 229.762 us; speedup vs baseline: 1.1354x; 1.1354x over previous
//
#include <hip/hip_runtime.h>

#define DD 128
#define RPT 4   // rows per thread

typedef float f32x4 __attribute__((ext_vector_type(4)));

// 32 lanes per row, one float4 per lane (fully coalesced: one load instruction
// covers 1 KiB contiguous). Each thread processes RPT rows from RPT disjoint
// chunks so all RPT loads are independent and issued before any dependent use
// (memory-level parallelism). Decode per row: local argmax over 4 elems,
// 2-step butterfly within aligned 4-lane groups, then 4 broadcasts.
__global__ __launch_bounds__(256) void byteshift_kernel(const float* __restrict__ x,
                                                        float* __restrict__ out,
                                                        int n_rows) {
    int tid = blockIdx.x * blockDim.x + threadIdx.x;
    int lane_r = tid & 31;              // lane within the 32-lane row group
    int row0 = tid >> 5;
    int nchunk = (n_rows + RPT - 1) / RPT;
    if (row0 >= nchunk) return;

    int dbase = lane_r * 4;             // this lane's global d base

    // issue all RPT coalesced loads up front
    f32x4 v[RPT];
    int rows[RPT];
    #pragma unroll
    for (int q = 0; q < RPT; ++q) {
        rows[q] = row0 + q * nchunk;
        if (rows[q] < n_rows)
            v[q] = ((const f32x4*)(x + (size_t)rows[q] * DD))[lane_r];
    }

    #pragma unroll
    for (int q = 0; q < RPT; ++q) {
        if (rows[q] >= n_rows) continue;
        f32x4 vv = v[q];

        // local argmax (global d index, '>' keeps first occurrence)
        float m = vv.x; int mi = dbase;
        if (vv.y > m) { m = vv.y; mi = dbase + 1; }
        if (vv.z > m) { m = vv.z; mi = dbase + 2; }
        if (vv.w > m) { m = vv.w; mi = dbase + 3; }

        // butterfly argmax across each aligned 4-lane group (one 16-elem slice)
        #pragma unroll
        for (int dlt = 1; dlt <= 2; dlt <<= 1) {
            float om = __shfl_xor(m, dlt);
            int   oi = __shfl_xor(mi, dlt);
            if (om > m || (om == m && oi < mi)) { m = om; mi = oi; }
        }

        // flags from lane 0 (d0 MARK >=0.5, d1 SHL >0.5, d2 SHR >0.5)
        int flags = (vv.x >= 0.5f ? 1 : 0) | (vv.y > 0.5f ? 2 : 0) | (vv.z > 0.5f ? 4 : 0);
        flags = __shfl(flags, 0, 32);

        // slice argmaxes: lanes 4-7 -> ALU_LO [16,32), 8-11 -> ALU_HI [32,48),
        // 12-15 -> AX_CARRY [48,64). Slices 16-aligned so (d & 15) is the index.
        int d_lo = __shfl(mi, 4, 32);
        int d_hi = __shfl(mi, 8, 32);
        int d_sh = __shfl(mi, 12, 32);

        int value = (d_lo & 15) | ((d_hi & 15) << 4);   // 0..255
        int shift = d_sh & 15;                           // <=15, min(.,31) no-op
        bool shl    = (flags & 2) != 0;
        bool active = (flags & 1) && (flags & 6);
        int result = shl ? ((value << shift) & 255) : (value >> shift);
        int t0 = 64 + (result & 15);
        int t1 = 80 + ((result >> 4) & 15);

        float add = active ? 2.0f : 0.0f;
        if (dbase     == t0 || dbase     == t1) vv.x += add;
        if (dbase + 1 == t0 || dbase + 1 == t1) vv.y += add;
        if (dbase + 2 == t0 || dbase + 2 == t1) vv.z += add;
        if (dbase + 3 == t0 || dbase + 3 == t1) vv.w += add;

        ((f32x4*)(out + (size_t)rows[q] * DD))[lane_r] = vv;
    }
}

extern "C" void kernel_launch(void* const* d_in, const int* in_sizes, int n_in,
                              void* d_out, int out_size, void* d_ws, size_t ws_size,
                              hipStream_t stream) {
    const float* x = (const float*)d_in[0];
    float* out = (float*)d_out;
    int n_rows = in_sizes[0] / DD;               // B*S = 262144
    int nchunk = (n_rows + RPT - 1) / RPT;       // rows handled per chunk
    int threads = 256;                           // 8 chunk-rows per block
    int total = nchunk * 32;
    int blocks = (total + threads - 1) / threads;
    hipLaunchKernelGGL(byteshift_kernel, dim3(blocks), dim3(threads), 0, stream,
                       x, out, n_rows);
}

// Round 5
// 219.494 us; speedup vs baseline: 1.1885x; 1.0468x over previous
//
#include <hip/hip_runtime.h>

#define DD 128

typedef float f32x4 __attribute__((ext_vector_type(4)));

// DPP helper: ctrl/masks must be compile-time constants for the builtin.
template <int CTRL, int RMASK>
__device__ __forceinline__ int dpp_i(int src) {
    // old=0, bank_mask=0xF, bound_ctrl=true (masked-off rows read old=0)
    return __builtin_amdgcn_update_dpp(0, src, CTRL, RMASK, 0xF, true);
}

// 32 lanes per row, one float4 per lane (one load instruction = 1 KiB
// contiguous). ALL cross-lane decode is DPP (VALU pipe, no LDS latency):
//   1) quad_perm butterfly argmax within each aligned 4-lane group
//      (= one 16-element one-hot slice),
//   2) pack slice nibbles + flags into one word w,
//   3) quad_perm([0,0,0,0]) OR: spread lane-0 flags to all of quad 0
//      (lane 15's ror-coset {15,3,7,11} now includes a flag-carrying lane),
//   4) OR-reduce w across the 16-lane DPP row (row_ror:4, row_ror:8),
//   5) row_bcast15 hands w to lanes 16-31 / 48-63 (targets t0/t1 in d 64..95).
__global__ __launch_bounds__(256) void byteshift_kernel(const float* __restrict__ x,
                                                        float* __restrict__ out,
                                                        int n_rows) {
    int tid = blockIdx.x * blockDim.x + threadIdx.x;
    int lane_r = tid & 31;      // lane within the 32-lane row group
    int row = tid >> 5;
    if (row >= n_rows) return;  // never taken (exact grid), keeps DPP exec full

    int dbase = lane_r * 4;
    f32x4 v = ((const f32x4*)(x + (size_t)row * DD))[lane_r];

    // local argmax over this lane's 4 elements ('>' keeps first occurrence)
    float m = v.x; int mi = dbase;
    if (v.y > m) { m = v.y; mi = dbase + 1; }
    if (v.z > m) { m = v.z; mi = dbase + 2; }
    if (v.w > m) { m = v.w; mi = dbase + 3; }

    // butterfly argmax across each aligned 4-lane group via DPP quad_perm
    {   // quad_perm [1,0,3,2] = 0xB1  (xor 1)
        float om = __int_as_float(dpp_i<0xB1, 0xF>(__float_as_int(m)));
        int   oi = dpp_i<0xB1, 0xF>(mi);
        if (om > m || (om == m && oi < mi)) { m = om; mi = oi; }
    }
    {   // quad_perm [2,3,0,1] = 0x4E  (xor 2)
        float om = __int_as_float(dpp_i<0x4E, 0xF>(__float_as_int(m)));
        int   oi = dpp_i<0x4E, 0xF>(mi);
        if (om > m || (om == m && oi < mi)) { m = om; mi = oi; }
    }

    // pack per-quad contribution into w:
    //   quad 1 (d16-31, ALU_LO)  -> bits [3:0]
    //   quad 2 (d32-47, ALU_HI)  -> bits [7:4]
    //   quad 3 (d48-63, CARRY)   -> bits [11:8]   (value <=15, min(.,31) no-op)
    //   lane 0 (d0-2 flags)      -> bits [14:12]
    int fl = (v.x >= 0.5f ? 1 : 0) | (v.y > 0.5f ? 2 : 0) | (v.z > 0.5f ? 4 : 0);
    int q = lane_r >> 2;
    int nib = mi & 15;          // slices are 16-aligned -> slice-local index
    int w = 0;
    if (q == 1) w = nib;
    else if (q == 2) w = nib << 4;
    else if (q == 3) w = nib << 8;
    if (lane_r == 0) w = fl << 12;

    // spread quad-lane-0 value across each quad (flags -> lanes 1-3 of quad 0;
    // no-op for quads 1-3 whose lanes already hold identical nibbles)
    w |= dpp_i<0x00, 0xF>(w);   // quad_perm [0,0,0,0]

    // OR-reduce across the 16-lane row, then broadcast into lanes 16-31
    w |= dpp_i<0x124, 0xF>(w);  // row_ror:4
    w |= dpp_i<0x128, 0xF>(w);  // row_ror:8  -> every lane 0-15 holds full w
    w |= dpp_i<0x142, 0xA>(w);  // row_bcast15 -> rows 1,3 (lanes 16-31 / 48-63)

    int value = w & 255;
    int shift = (w >> 8) & 15;
    int flg   = (w >> 12) & 7;
    bool shl    = (flg & 2) != 0;
    bool active = (flg & 1) && (flg & 6);
    int result  = shl ? ((value << shift) & 255) : (value >> shift);
    int t0 = 64 + (result & 15);
    int t1 = 80 + (result >> 4);

    float add = active ? 2.0f : 0.0f;
    if (dbase     == t0 || dbase     == t1) v.x += add;
    if (dbase + 1 == t0 || dbase + 1 == t1) v.y += add;
    if (dbase + 2 == t0 || dbase + 2 == t1) v.z += add;
    if (dbase + 3 == t0 || dbase + 3 == t1) v.w += add;

    ((f32x4*)(out + (size_t)row * DD))[lane_r] = v;
}

extern "C" void kernel_launch(void* const* d_in, const int* in_sizes, int n_in,
                              void* d_out, int out_size, void* d_ws, size_t ws_size,
                              hipStream_t stream) {
    const float* x = (const float*)d_in[0];
    float* out = (float*)d_out;
    int n_rows = in_sizes[0] / DD;      // B*S = 262144
    int threads = 256;                  // 8 rows per block
    int total = n_rows * 32;
    int blocks = (total + threads - 1) / threads;
    hipLaunchKernelGGL(byteshift_kernel, dim3(blocks), dim3(threads), 0, stream,
                       x, out, n_rows);
}